// Round 7
// baseline (161.095 us; speedup 1.0000x reference)
//
#include <hip/hip_runtime.h>

// Viterbi trellis quantizer: S=1024 states, K=2 (4 predecessors), CHUNK=4,
// block_size=16 -> T=64 steps/chain, B=4096 chains (16x16 blocks of 1024^2).
//
// One 64-lane wave per chain (R3's proven-best decomposition).
// beta-formulation: beta_t[s] = M_{t-1}[s>>2] + (cb[s]·x_t + h[s]),
//   h = -||cb||^2/2, M_t[p] = max_j beta_t[p + 256j], M_{-1} = 0.
// Lane L owns states s = 4L + c + 256j (c,j in 0..3): produces M[4L+c],
// consumes M[L + 64j]; 2-bit backpointer per group.
//
// R9. Evidence: R3=57.5us (4w/SIMD TLP), R6=66 (2-chain ILP), R7=63
// (8w/SIMD residency), R8=77 (barrier amortization) -- every decomposition
// fails the same way because the per-step stall is PROGRAM ORDER, not
// resources: read M (stall ~120cyc) -> dots -> write. The 64 dot-FMAs are
// M-INDEPENDENT but scheduled after the stalled read.
// Fix: explicit software pipeline. Iteration t:
//   issue mj reads -> compute dot_{t+1} (64 indep FMAs cover the read
//   latency) -> cand = dot_t(regs) + mj -> max/sel -> write M, J.
// Plus 2-deep xt prefetch so dot_{t+1}'s input is ready. Static double
// buffers via paired macro (no runtime indexing -> no scratch).
// Numerics: fmaf chain + "+mj" order unchanged -> bit-identical to R3.
// waves_per_eu(3,4): honest ~170-reg budget for ~140 demand (no spill;
// residency proven non-binding in R7 -- spend registers on ILP).
// Tripwire: WRITE_SIZE > 5120 KB = spill -> shrink pipeline depth.

#define COLS      1024
#define T_STEPS   64
#define REC_SIZE  (1024 * 1024)

__global__ __launch_bounds__(128)
__attribute__((amdgpu_waves_per_eu(3, 4)))
void viterbi_q(
    const float* __restrict__ arr,
    const float* __restrict__ cbook,
    float* __restrict__ out)
{
    const int tid   = threadIdx.x;
    const int wid   = tid >> 6;      // chain slot in block (0..1)
    const int lane  = tid & 63;
    const int chain = (blockIdx.x << 1) | wid;   // 0..4095
    const int rb    = chain >> 6;    // block-row
    const int cb    = chain & 63;    // block-col

    __shared__ __align__(16) float tile[2][256];   // x chunks for the chain
    __shared__ __align__(16) float Mst[2][256];    // grouped-max state M[p]
    __shared__ unsigned char Jb[2][63 * 64];       // packed backpointers
    __shared__ int st_lds[2][64];                  // traced-back states

    // ---- stage this chain's 16x16 tile into LDS (tile[e], e = r*16 + c) ----
    {
        const int r  = lane >> 2;
        const int c4 = (lane & 3) << 2;
        float4 v = *(const float4*)(arr + (rb * 16 + r) * COLS + cb * 16 + c4);
        *(float4*)&tile[wid][lane << 2] = v;
    }
    // M starts at 0: step 0 then computes beta0 = cb·x0 + h exactly.
    *(float4*)&Mst[wid][lane << 2] = make_float4(0.f, 0.f, 0.f, 0.f);

    // ---- codebook rows for this lane's 16 states: s = 4*lane + c + 256*j ----
    float4 a[16];   // raw codebook row
    float  h[16];   // -||row||^2 / 2
    #pragma unroll
    for (int j = 0; j < 4; ++j) {
        #pragma unroll
        for (int c = 0; c < 4; ++c) {
            const int row = (lane << 2) + c + (j << 8);
            float4 v = *(const float4*)(cbook + row * 4);
            a[j * 4 + c] = v;
            h[j * 4 + c] = -0.5f * (v.x * v.x + v.y * v.y +
                                    v.z * v.z + v.w * v.w);
        }
    }

    // hoisted LDS pointers
    const float* __restrict__ tilep = &tile[wid][0];
    float* __restrict__ Mp          = &Mst[wid][0];
    unsigned char* __restrict__ Jp  = &Jb[wid][0];

    // D[(c<<2)|j] = cb[s]·X + h[s]  for this lane's 16 states.
    // Same fmaf chain order as R3 -> bit-identical values.
#define DOT16(D, X)                                                           \
    _Pragma("unroll")                                                         \
    for (int c = 0; c < 4; ++c) {                                             \
        _Pragma("unroll")                                                     \
        for (int j = 0; j < 4; ++j) {                                         \
            const float4 av = a[j * 4 + c];                                   \
            float acc = fmaf(av.x, (X).x, h[j * 4 + c]);                      \
            acc = fmaf(av.y, (X).y, acc);                                     \
            acc = fmaf(av.z, (X).z, acc);                                     \
            acc = fmaf(av.w, (X).w, acc);                                     \
            (D)[(c << 2) | j] = acc;                                          \
        }                                                                     \
    }

    // One pipelined forward step T (0..62):
    //  - mj reads issued first (latency covered by the DOT16 below)
    //  - XNXT <- x_{T+2} (2-deep prefetch; &63 clamps the T=62 overread)
    //  - DNXT <- dot_{T+1} from XCUR (M-independent cover work)
    //  - cand = DCUR + mj; max/sel/pack; write M_T, J_T.
#define STEP(T, DCUR, DNXT, XCUR, XNXT)                                       \
    {                                                                         \
        float mj[4];                                                          \
        _Pragma("unroll")                                                     \
        for (int j = 0; j < 4; ++j) mj[j] = Mp[lane + (j << 6)];              \
        XNXT = *(const float4*)&tilep[(((T) + 2) & 63) << 2];                 \
        DOT16(DNXT, XCUR)                                                     \
        float nm[4];                                                          \
        unsigned bp = 0;                                                      \
        _Pragma("unroll")                                                     \
        for (int c = 0; c < 4; ++c) {                                         \
            float cand[4];                                                    \
            _Pragma("unroll")                                                 \
            for (int j = 0; j < 4; ++j)                                       \
                cand[j] = (DCUR)[(c << 2) | j] + mj[j];                       \
            const float v = fmaxf(fmaxf(fmaxf(cand[0], cand[1]), cand[2]),    \
                                  cand[3]);                                   \
            const int j = (cand[0] == v) ? 0                                  \
                        : (cand[1] == v) ? 1                                  \
                        : (cand[2] == v) ? 2 : 3;                             \
            nm[c] = v;                                                        \
            bp |= (unsigned)j << (2 * c);                                     \
        }                                                                     \
        *(float4*)&Mp[lane << 2] = make_float4(nm[0], nm[1], nm[2], nm[3]);   \
        Jp[(T) * 64 + lane] = (unsigned char)bp;                              \
    }

    // ---- prologue: dot_0 from x_0; x_1 staged as XCUR for iteration 0 ----
    float dA[16], dB[16];
    float4 xC, xD;
    {
        const float4 x0 = *(const float4*)&tilep[0];
        DOT16(dA, x0)                 // dA = dot_0
        xC = *(const float4*)&tilep[4];   // x_1
    }

    // ---- forward recursion, t = 0..61 paired + t = 62 ----
    #pragma unroll 1
    for (int t = 0; t < 62; t += 2) {
        STEP(t,     dA, dB, xC, xD)   // consumes dot_t, builds dot_{t+1}
        STEP(t + 1, dB, dA, xD, xC)
    }
    STEP(62, dA, dB, xC, xD)          // writes M_62/J_62; dB = dot_63
#undef STEP

    // ---- final step t = 63: full argmax over beta_63[0..1023] ----
    int bests;
    {
        float mj[4];
        #pragma unroll
        for (int j = 0; j < 4; ++j) mj[j] = Mp[lane + (j << 6)];

        float bv = -3.4e38f;
        int   bs = 0;
        #pragma unroll
        for (int j = 0; j < 4; ++j) {      // s ascends with (j, c): first-max ok
            #pragma unroll
            for (int c = 0; c < 4; ++c) {
                const float acc = dB[(c << 2) | j] + mj[j];
                if (acc > bv) { bv = acc; bs = (lane << 2) + c + (j << 8); }
            }
        }
        // lexicographic (value desc, state asc) butterfly across the wave
        #pragma unroll
        for (int off = 32; off > 0; off >>= 1) {
            const float ov = __shfl_xor(bv, off, 64);
            const int   os = __shfl_xor(bs, off, 64);
            if (ov > bv || (ov == bv && os < bs)) { bv = ov; bs = os; }
        }
        bests = bs;
    }

    // ---- traceback (serial, lane 0 of each wave) ----
    if (lane == 0) {
        int s = bests;
        st_lds[wid][T_STEPS - 1] = s;
        for (int i = T_STEPS - 2; i >= 0; --i) {
            const int p = s >> 2;
            const unsigned byte = Jp[i * 64 + (p >> 2)];
            const int j = (byte >> (2 * (p & 3))) & 3;
            s = p + (j << 8);
            st_lds[wid][i] = s;
        }
    }
    // NO barrier: st_lds[wid] is written by lane 0 of THIS wave and read by
    // the same wave below; wave-lockstep + in-order same-wave DS ordering.

    // ---- outputs: lane i handles step t = i ----
    const int st = st_lds[wid][lane];
    // states_out flat: REC_SIZE + chain*64 + t   (stored as float values)
    out[REC_SIZE + chain * 64 + lane] = (float)st;
    // rec: step t covers elements e = 4t..4t+3 -> row t>>2, cols 4*(t&3)..+3
    const float4 v = *(const float4*)(cbook + st * 4);
    const int r  = lane >> 2;
    const int c4 = (lane & 3) << 2;
    *(float4*)(out + (rb * 16 + r) * COLS + cb * 16 + c4) = v;
}

extern "C" void kernel_launch(void* const* d_in, const int* in_sizes, int n_in,
                              void* d_out, int out_size, void* d_ws, size_t ws_size,
                              hipStream_t stream)
{
    const float* arr   = (const float*)d_in[0];
    const float* cbook = (const float*)d_in[1];
    float* out = (float*)d_out;
    // 4096 chains, 2 chains (waves) per 128-thread block -> 2048 blocks
    viterbi_q<<<dim3(2048), dim3(128), 0, stream>>>(arr, cbook, out);
}

// Round 8
// 115.819 us; speedup vs baseline: 1.3909x; 1.3909x over previous
//
#include <hip/hip_runtime.h>

// Viterbi trellis quantizer: S=1024 states, K=2 (4 predecessors), CHUNK=4,
// block_size=16 -> T=64 steps/chain, B=4096 chains (16x16 blocks of 1024^2).
//
// One 64-lane wave per chain (R3's proven-best decomposition).
// beta-formulation: beta_t[s] = M_{t-1}[s>>2] + (cb[s]·x_t + h[s]),
//   h = -||cb||^2/2, M_t[p] = max_j beta_t[p + 256j], M_{-1} = 0.
// Lane L: consumes M[L+64j], produces M[4L+c] (nm[c]), 2-bit J per group.
//
// R10. R9's double-buffered pipeline spilled (WRITE_SIZE 5120->36550 KB;
// budget keys off waves_per_eu MAX: (3,4) -> 512/4 = 128 < ~168 demand).
// The pipeline theory is untested, not refuted. Fix the footprint:
//  1. SINGLE dot buffer: the only latency to cover at step t is the mj read
//     of M_{t-1}; dot_t is M-independent, so compute it AFTER issuing the
//     mj reads within the same iteration (64 indep FMAs ~128 issue-cyc
//     cover the ~120-240cyc LDS read-after-write latency). No dot_{t+1}
//     buffer needed -> -24 live regs vs R9.
//  2. 1-deep xt prefetch only (xt_{t+1} read issued alongside mj reads).
//  3. waves_per_eu(3,3): budget 170 whether keyed off min or max; demand
//     ~145 -> no spill, 3 waves/EU (R3's occupancy -- proven non-binding
//     in R7, so any win is pure stall removal).
// Numerics: fmaf chain + "+mj" order == R3 -> bit-identical decisions.
// Tripwire: WRITE_SIZE > 5120 KB = spill. FETCH_SIZE must return to ~2173.

#define COLS      1024
#define T_STEPS   64
#define REC_SIZE  (1024 * 1024)

__global__ __launch_bounds__(128)
__attribute__((amdgpu_waves_per_eu(3, 3)))
void viterbi_q(
    const float* __restrict__ arr,
    const float* __restrict__ cbook,
    float* __restrict__ out)
{
    const int tid   = threadIdx.x;
    const int wid   = tid >> 6;      // chain slot in block (0..1)
    const int lane  = tid & 63;
    const int chain = (blockIdx.x << 1) | wid;   // 0..4095
    const int rb    = chain >> 6;    // block-row
    const int cb    = chain & 63;    // block-col

    __shared__ __align__(16) float tile[2][256];   // x chunks for the chain
    __shared__ __align__(16) float Mst[2][256];    // grouped-max state M[p]
    __shared__ unsigned char Jb[2][63 * 64];       // packed backpointers
    __shared__ int st_lds[2][64];                  // traced-back states

    // ---- stage this chain's 16x16 tile into LDS (tile[e], e = r*16 + c) ----
    {
        const int r  = lane >> 2;
        const int c4 = (lane & 3) << 2;
        float4 v = *(const float4*)(arr + (rb * 16 + r) * COLS + cb * 16 + c4);
        *(float4*)&tile[wid][lane << 2] = v;
    }
    // M starts at 0: step 0 then computes beta0 = cb·x0 + h exactly.
    *(float4*)&Mst[wid][lane << 2] = make_float4(0.f, 0.f, 0.f, 0.f);

    // ---- codebook rows for this lane's 16 states: s = 4*lane + c + 256*j ----
    float4 a[16];   // raw codebook row
    float  h[16];   // -||row||^2 / 2
    #pragma unroll
    for (int j = 0; j < 4; ++j) {
        #pragma unroll
        for (int c = 0; c < 4; ++c) {
            const int row = (lane << 2) + c + (j << 8);
            float4 v = *(const float4*)(cbook + row * 4);
            a[j * 4 + c] = v;
            h[j * 4 + c] = -0.5f * (v.x * v.x + v.y * v.y +
                                    v.z * v.z + v.w * v.w);
        }
    }

    // hoisted LDS pointers
    const float* __restrict__ tilep = &tile[wid][0];
    float* __restrict__ Mp          = &Mst[wid][0];
    unsigned char* __restrict__ Jp  = &Jb[wid][0];

    // D[(c<<2)|j] = cb[s]·X + h[s] for this lane's 16 states.
    // Same fmaf chain order as R3 -> bit-identical values.
#define DOT16(D, X)                                                           \
    _Pragma("unroll")                                                         \
    for (int c = 0; c < 4; ++c) {                                             \
        _Pragma("unroll")                                                     \
        for (int j = 0; j < 4; ++j) {                                         \
            const float4 av = a[j * 4 + c];                                   \
            float acc = fmaf(av.x, (X).x, h[j * 4 + c]);                      \
            acc = fmaf(av.y, (X).y, acc);                                     \
            acc = fmaf(av.z, (X).z, acc);                                     \
            acc = fmaf(av.w, (X).w, acc);                                     \
            (D)[(c << 2) | j] = acc;                                          \
        }                                                                     \
    }

    float d[16];
    float4 xc = *(const float4*)&tilep[0];   // x_0 (prefetched)

    // ---- forward recursion, t = 0..62 ----
    // Per iteration: issue mj reads (latency target) + x_{t+1} prefetch,
    // then 64 M-independent FMAs (cover), then consume mj, write M_t, J_t.
    #pragma unroll 1
    for (int t = 0; t < T_STEPS - 1; ++t) {
        float mj[4];
        #pragma unroll
        for (int j = 0; j < 4; ++j) mj[j] = Mp[lane + (j << 6)];
        const float4 xn = *(const float4*)&tilep[(t + 1) << 2];

        DOT16(d, xc)                 // dot_t: independent of the mj reads

        float nm[4];
        unsigned bp = 0;
        #pragma unroll
        for (int c = 0; c < 4; ++c) {
            float cand[4];
            #pragma unroll
            for (int j = 0; j < 4; ++j)
                cand[j] = d[(c << 2) | j] + mj[j];
            const float v = fmaxf(fmaxf(fmaxf(cand[0], cand[1]), cand[2]),
                                  cand[3]);
            // first-max index == reference's first-min over alpha candidates
            const int j = (cand[0] == v) ? 0
                        : (cand[1] == v) ? 1
                        : (cand[2] == v) ? 2 : 3;
            nm[c] = v;
            bp |= (unsigned)j << (2 * c);
        }
        // wave-lockstep: all lanes issued their M reads above before this write
        *(float4*)&Mp[lane << 2] = make_float4(nm[0], nm[1], nm[2], nm[3]);
        Jp[t * 64 + lane] = (unsigned char)bp;
        xc = xn;
    }

    // ---- final step t = 63: full argmax over beta_63[0..1023] ----
    int bests;
    {
        float mj[4];
        #pragma unroll
        for (int j = 0; j < 4; ++j) mj[j] = Mp[lane + (j << 6)];

        DOT16(d, xc)                 // dot_63 (xc = x_63 from last prefetch)

        float bv = -3.4e38f;
        int   bs = 0;
        #pragma unroll
        for (int j = 0; j < 4; ++j) {      // s ascends with (j, c): first-max ok
            #pragma unroll
            for (int c = 0; c < 4; ++c) {
                const float acc = d[(c << 2) | j] + mj[j];
                if (acc > bv) { bv = acc; bs = (lane << 2) + c + (j << 8); }
            }
        }
        // lexicographic (value desc, state asc) butterfly across the wave
        #pragma unroll
        for (int off = 32; off > 0; off >>= 1) {
            const float ov = __shfl_xor(bv, off, 64);
            const int   os = __shfl_xor(bs, off, 64);
            if (ov > bv || (ov == bv && os < bs)) { bv = ov; bs = os; }
        }
        bests = bs;
    }
#undef DOT16

    // ---- traceback (serial, lane 0 of each wave) ----
    if (lane == 0) {
        int s = bests;
        st_lds[wid][T_STEPS - 1] = s;
        for (int i = T_STEPS - 2; i >= 0; --i) {
            const int p = s >> 2;
            const unsigned byte = Jp[i * 64 + (p >> 2)];
            const int j = (byte >> (2 * (p & 3))) & 3;
            s = p + (j << 8);
            st_lds[wid][i] = s;
        }
    }
    // NO barrier: st_lds[wid] is written by lane 0 of THIS wave and read by
    // the same wave below; wave-lockstep + in-order same-wave DS ordering.

    // ---- outputs: lane i handles step t = i ----
    const int st = st_lds[wid][lane];
    // states_out flat: REC_SIZE + chain*64 + t   (stored as float values)
    out[REC_SIZE + chain * 64 + lane] = (float)st;
    // rec: step t covers elements e = 4t..4t+3 -> row t>>2, cols 4*(t&3)..+3
    const float4 v = *(const float4*)(cbook + st * 4);
    const int r  = lane >> 2;
    const int c4 = (lane & 3) << 2;
    *(float4*)(out + (rb * 16 + r) * COLS + cb * 16 + c4) = v;
}

extern "C" void kernel_launch(void* const* d_in, const int* in_sizes, int n_in,
                              void* d_out, int out_size, void* d_ws, size_t ws_size,
                              hipStream_t stream)
{
    const float* arr   = (const float*)d_in[0];
    const float* cbook = (const float*)d_in[1];
    float* out = (float*)d_out;
    // 4096 chains, 2 chains (waves) per 128-thread block -> 2048 blocks
    viterbi_q<<<dim3(2048), dim3(128), 0, stream>>>(arr, cbook, out);
}